// Round 1
// baseline (899.122 us; speedup 1.0000x reference)
//
#include <hip/hip_runtime.h>
#include <hip/hip_cooperative_groups.h>

namespace cg = cooperative_groups;

#define N_NODES 50000
#define N_EDGES 800000
#define BATCH   32
#define NWORD8  12500   // N_NODES/4 u32 words (u8-packed deg counts / qd8 table)
#define NWORDC  25000   // N_NODES/2 u32 words, u16-packed c (full range, 100 KB)
#define CHUNKS  8       // edge chunks for both hist and cscat (100K edges each)
#define EPC4    25000   // int4 edge loads per chunk (= 100000 edges)
#define QSCALE  255.0f
#define ACTIVE  1020    // pool threads: 1020*4 % 10 == 0 keeps per-lane phase const
#define DYNLDS  ((NWORDC + NWORD8) * 4)   // 150 KB dynamic LDS (max over phases)

// ---------------------------------------------------------------------------
// One persistent cooperative kernel, 256 blocks x 1024 threads, 1 block/CU.
// Phases separated by grid.sync():
//   P1 hist:  per-(b,oct) degree histogram (u8 packed x4) -> partials (12.8 MB)
//   P2 dinv:  reduce 8 partials -> dinv f32 + qd8 u8-packed
//   P3 cscat: c[src] += qdinv[dst], u16 LDS histogram over full node range
//   P4 pool:  w-slice computed into LDS (K4 folded in), weighted column-sum
//   P5 mlp:   block 0 only: reduce partials + MLP + log_softmax(axis=0)
// ---------------------------------------------------------------------------
__global__ __launch_bounds__(1024, 1) void mega_kernel(
    const int* __restrict__ ei, const float* __restrict__ xg,
    const float* __restrict__ x,
    const float* __restrict__ W_gcn, const float* __restrict__ b_gcn,
    const float* __restrict__ W1, const float* __restrict__ b1,
    const float* __restrict__ W2, const float* __restrict__ b2,
    const float* __restrict__ Wo, const float* __restrict__ bo,
    unsigned* __restrict__ partials,   // 25.6 MB region: hist partials, then cpart
    float* __restrict__ dinv,
    unsigned* __restrict__ qd8,
    float* __restrict__ spart,
    float* __restrict__ out)
{
    extern __shared__ unsigned smem[];
    cg::grid_group grid = cg::this_grid();
    const int bid = blockIdx.x;
    const int tid = threadIdx.x;

    // ---- P1: degree histogram, 8 chunks of 100K edges, LDS u8x4 counters ----
    {
        unsigned* cnt = smem;  // 50 KB
        for (int i = tid; i < NWORD8; i += 1024) cnt[i] = 0;
        __syncthreads();
        const int b = bid >> 3, oct = bid & 7;
        const int4* __restrict__ dst4 =
            (const int4*)(ei + (size_t)b * (2 * N_EDGES) + N_EDGES) + (size_t)oct * EPC4;
        for (int i = tid; i < EPC4; i += 1024) {
            const int4 v = dst4[i];
            atomicAdd(&cnt[((unsigned)v.x) >> 2], 1u << ((v.x & 3) * 8));
            atomicAdd(&cnt[((unsigned)v.y) >> 2], 1u << ((v.y & 3) * 8));
            atomicAdd(&cnt[((unsigned)v.z) >> 2], 1u << ((v.z & 3) * 8));
            atomicAdd(&cnt[((unsigned)v.w) >> 2], 1u << ((v.w & 3) * 8));
        }
        __syncthreads();
        unsigned* __restrict__ o8 = partials + (size_t)bid * NWORD8;  // bid == b*8+oct
        for (int i = tid; i < NWORD8; i += 1024) o8[i] = cnt[i];
    }
    __threadfence();
    grid.sync();

    // ---- P2: reduce partials -> dinv (f32) + qd8 (u8 packed) ----
    for (int idx = bid * 1024 + tid; idx < BATCH * NWORD8; idx += 256 * 1024) {
        const int b = idx / NWORD8, i = idx - b * NWORD8;
        const unsigned* __restrict__ p = partials + (size_t)(b * CHUNKS) * NWORD8 + i;
        unsigned d0 = 0, d1 = 0, d2 = 0, d3 = 0;
#pragma unroll
        for (int c = 0; c < CHUNKS; ++c) {
            const unsigned v = p[(size_t)c * NWORD8];
            d0 += v & 0xFF; d1 += (v >> 8) & 0xFF; d2 += (v >> 16) & 0xFF; d3 += v >> 24;
        }
        const float i0 = rsqrtf((float)(d0 + 1));
        const float i1 = rsqrtf((float)(d1 + 1));
        const float i2 = rsqrtf((float)(d2 + 1));
        const float i3 = rsqrtf((float)(d3 + 1));
        float4* dv4 = (float4*)(dinv + (size_t)b * N_NODES) + i;
        *dv4 = make_float4(i0, i1, i2, i3);
        const unsigned q0 = __float2uint_rn(i0 * QSCALE);
        const unsigned q1 = __float2uint_rn(i1 * QSCALE);
        const unsigned q2 = __float2uint_rn(i2 * QSCALE);
        const unsigned q3 = __float2uint_rn(i3 * QSCALE);
        qd8[(size_t)b * NWORD8 + i] = q0 | (q1 << 8) | (q2 << 16) | (q3 << 24);
    }
    __threadfence();
    grid.sync();

    // ---- P3: c-scatter, u16 LDS histogram + u8 dinv gather table in LDS ----
    {
        unsigned* cs = smem;                                     // 100 KB
        const unsigned char* qs = (const unsigned char*)(smem + NWORDC);  // 50 KB
        const int b = bid & 31, chunk = bid >> 5;  // batch b's 8 chunks share one XCD
        for (int i = tid; i < NWORDC; i += 1024) cs[i] = 0;
        const unsigned* __restrict__ qsrc = qd8 + (size_t)b * NWORD8;
        for (int i = tid; i < NWORD8; i += 1024) smem[NWORDC + i] = qsrc[i];
        __syncthreads();
        const int* eb = ei + (size_t)b * (2 * N_EDGES);
        const int4* __restrict__ s4p = (const int4*)eb + (size_t)chunk * EPC4;
        const int4* __restrict__ d4p = (const int4*)(eb + N_EDGES) + (size_t)chunk * EPC4;
        for (int i = tid; i < EPC4; i += 1024) {
            const int4 s4 = s4p[i];
            const int4 d4 = d4p[i];
            const unsigned q0 = qs[d4.x];
            const unsigned q1 = qs[d4.y];
            const unsigned q2 = qs[d4.z];
            const unsigned q3 = qs[d4.w];
            atomicAdd(&cs[((unsigned)s4.x) >> 1], q0 << ((s4.x & 1) << 4));
            atomicAdd(&cs[((unsigned)s4.y) >> 1], q1 << ((s4.y & 1) << 4));
            atomicAdd(&cs[((unsigned)s4.z) >> 1], q2 << ((s4.z & 1) << 4));
            atomicAdd(&cs[((unsigned)s4.w) >> 1], q3 << ((s4.w & 1) << 4));
        }
        __syncthreads();
        unsigned* __restrict__ op = partials + (size_t)(b * CHUNKS + chunk) * NWORDC;
        for (int i = tid; i < NWORDC; i += 1024) op[i] = cs[i];
    }
    __threadfence();
    grid.sync();

    // ---- P4: w-slice into LDS (K4 folded in) + pooled weighted column-sum ----
    {
        float* wlds = (float*)smem;              // 6250 f32 = 25 KB
        float* sacc = (float*)smem + 6256;       // [16][10] wave accumulators
        const int c = bid & 7, b = bid >> 3;
        const int wbase = c * (NWORDC / 8);      // 3125 words -> 6250 nodes
        for (int i = tid; i < NWORDC / 8; i += 1024) {
            const unsigned* __restrict__ p =
                partials + (size_t)(b * CHUNKS) * NWORDC + wbase + i;
            unsigned c0 = 0, c1 = 0;
#pragma unroll
            for (int ch = 0; ch < CHUNKS; ++ch) {
                const unsigned v = p[(size_t)ch * NWORDC];
                c0 += v & 0xFFFF; c1 += v >> 16;
            }
            const int node = 2 * (wbase + i);
            const float2 d = *((const float2*)(dinv + (size_t)b * N_NODES + node));
            wlds[2 * i]     = d.x * ((float)c0 * (1.0f / QSCALE) + d.x);
            wlds[2 * i + 1] = d.y * ((float)c1 * (1.0f / QSCALE) + d.y);
        }
        const int wave = tid >> 6;
        if ((tid & 63) < 10) sacc[wave * 10 + (tid & 63)] = 0.0f;
        __syncthreads();
        if (tid < ACTIVE) {
            const float4* __restrict__ xg4 = (const float4*)xg;
            const int base4 = b * 125000 + c * 15625;   // slice-aligned: 4*base4 % 10 == 0
            const int r = (4 * tid) % 10;               // channel phase, fixed per lane
            float a0 = 0.0f, a1 = 0.0f, a2 = 0.0f, a3 = 0.0f;
            for (int j = tid; j < 15625; j += ACTIVE) {
                const float4 v = xg4[base4 + j];
                const int ln = (4 * j) / 10;            // local node in [0,6250)
                const float w0 = wlds[ln];
                const float w1 = (r == 8) ? wlds[ln + 1] : w0;  // r==8: z,w cross node
                a0 += v.x * w0;
                a1 += v.y * w0;
                a2 += v.z * w1;
                a3 += v.w * w1;
            }
            atomicAdd(&sacc[wave * 10 + r], a0);
            atomicAdd(&sacc[wave * 10 + (r + 1) % 10], a1);
            atomicAdd(&sacc[wave * 10 + (r + 2) % 10], a2);
            atomicAdd(&sacc[wave * 10 + (r + 3) % 10], a3);
        }
        __syncthreads();
        if (tid < 10) {
            float v = 0.0f;
#pragma unroll
            for (int wv = 0; wv < 16; ++wv) v += sacc[wv * 10 + tid];
            spart[(b * CHUNKS + c) * 16 + tid] = v;
        }
    }
    __threadfence();
    grid.sync();

    // ---- P5: reduce pool partials + tiny MLP + log_softmax(axis=0), block 0 ----
    if (bid == 0) {
        float* fs   = (float*)smem;
        float* ssum = fs;           // [32][10]
        float* h0   = fs + 320;     // [32][20]
        float* h1   = fs + 960;     // [32][80]
        float* h2   = fs + 3520;    // [32][160]
        float* o    = fs + 8640;    // [32][4]

        for (int idx = tid; idx < 32 * 10; idx += 1024) {
            const int b = idx / 10, k = idx % 10;
            float v = 0.0f;
#pragma unroll
            for (int c = 0; c < CHUNKS; ++c) v += spart[(b * CHUNKS + c) * 16 + k];
            ssum[b * 10 + k] = v;
        }
        __syncthreads();

        for (int idx = tid; idx < 32 * 20; idx += 1024) {
            const int b = idx / 20, j = idx % 20;
            float v;
            if (j < 10) {
                v = 0.0f;
#pragma unroll
                for (int k = 0; k < 10; ++k) v += ssum[b * 10 + k] * W_gcn[k * 10 + j];
                v = v * (1.0f / (float)N_NODES) + b_gcn[j];
            } else {
                v = x[b * 10 + (j - 10)];
            }
            h0[b * 20 + j] = v;
        }
        __syncthreads();

        for (int idx = tid; idx < 32 * 80; idx += 1024) {
            const int b = idx / 80, j = idx % 80;
            float v = b1[j];
#pragma unroll
            for (int k = 0; k < 20; ++k) v += h0[b * 20 + k] * W1[k * 80 + j];
            h1[b * 80 + j] = (v > 0.0f) ? v : 0.01f * v;
        }
        __syncthreads();

        for (int idx = tid; idx < 32 * 160; idx += 1024) {
            const int b = idx / 160, j = idx % 160;
            float v = b2[j];
            for (int k = 0; k < 80; ++k) v += h1[b * 80 + k] * W2[k * 160 + j];
            h2[b * 160 + j] = (v > 0.0f) ? v : 0.01f * v;
        }
        __syncthreads();

        for (int idx = tid; idx < 32 * 4; idx += 1024) {
            const int b = idx / 4, j = idx % 4;
            float v = bo[j];
            for (int k = 0; k < 160; ++k) v += h2[b * 160 + k] * Wo[k * 4 + j];
            o[b * 4 + j] = v;
        }
        __syncthreads();

        if (tid < 4) {
            float m = -1e30f;
            for (int b = 0; b < 32; ++b) m = fmaxf(m, o[b * 4 + tid]);
            float lse = 0.0f;
            for (int b = 0; b < 32; ++b) lse += expf(o[b * 4 + tid] - m);
            lse = logf(lse);
            for (int b = 0; b < 32; ++b) out[b * 4 + tid] = o[b * 4 + tid] - m - lse;
        }
    }
}

extern "C" void kernel_launch(void* const* d_in, const int* in_sizes, int n_in,
                              void* d_out, int out_size, void* d_ws, size_t ws_size,
                              hipStream_t stream) {
    (void)in_sizes; (void)n_in; (void)out_size; (void)ws_size;
    const float* x      = (const float*)d_in[0];
    const float* gcn_x  = (const float*)d_in[1];
    const int*   ei     = (const int*)d_in[2];
    const float* W_gcn  = (const float*)d_in[3];
    const float* b_gcn  = (const float*)d_in[4];
    const float* W1     = (const float*)d_in[5];
    const float* b1     = (const float*)d_in[6];
    const float* W2     = (const float*)d_in[7];
    const float* b2     = (const float*)d_in[8];
    const float* Wo     = (const float*)d_in[9];
    const float* bo     = (const float*)d_in[10];
    float* out = (float*)d_out;

    // workspace layout (bytes):
    //   partials [32*8*25000 u32]  @ 0           (25.6 MB; hist-u8 then cpart-u16)
    //   dinv     [32*50000 f32]    @ 25,600,000  (6.4 MB)
    //   qd8      [32*12500 u32]    @ 32,000,000  (1.6 MB)
    //   spart    [32*8*16 f32]     @ 33,600,000  (16 KB)     total ~33.6 MB
    unsigned* partials = (unsigned*)d_ws;
    float*    dinv     = (float*)((char*)d_ws + (size_t)BATCH * CHUNKS * NWORDC * 4);
    unsigned* qd8      = (unsigned*)((char*)dinv + (size_t)BATCH * N_NODES * 4);
    float*    spart    = (float*)((char*)qd8 + (size_t)BATCH * NWORD8 * 4);

    hipFuncSetAttribute((const void*)mega_kernel,
                        hipFuncAttributeMaxDynamicSharedMemorySize, DYNLDS);

    void* args[] = {
        (void*)&ei, (void*)&gcn_x, (void*)&x,
        (void*)&W_gcn, (void*)&b_gcn,
        (void*)&W1, (void*)&b1, (void*)&W2, (void*)&b2,
        (void*)&Wo, (void*)&bo,
        (void*)&partials, (void*)&dinv, (void*)&qd8, (void*)&spart, (void*)&out
    };
    hipLaunchCooperativeKernel((void*)mega_kernel, dim3(256), dim3(1024),
                               args, DYNLDS, stream);
}

// Round 3
// 457.615 us; speedup vs baseline: 1.9648x; 1.9648x over previous
//
#include <hip/hip_runtime.h>

#define N_NODES 50000
#define N_EDGES 800000
#define BATCH   32
#define NWORD8  12500   // N_NODES/4 u32 words (u8-packed deg counts / qd8 table)
#define NWORDC  25000   // N_NODES/2 u32 words, u16-packed c (full range, 100 KB)
#define CHUNKS  8       // cscat chunks
#define EPC4    25000   // cscat int4 loads per chunk (= 100000 edges)
#define HCHUNKS 16      // hist chunks (512 blocks -> 2/CU)
#define HEPC4   12500   // hist int4 loads per chunk (= 50000 edges)
#define QSCALE  255.0f
#define ACTIVE  1020    // pool active threads: 1020*4 % 10 == 0 -> per-lane phase const

// ---------------------------------------------------------------------------
// K1: per-(batch,chunk) degree histogram in LDS (u8 packed x4 per u32 word).
// 16 chunks -> 512 blocks -> 2 blocks/CU (32 waves). No global atomics.
// ---------------------------------------------------------------------------
__global__ __launch_bounds__(1024) void hist_kernel(const int* __restrict__ ei,
                                                    unsigned* __restrict__ partials) {
    const int chunk = blockIdx.x, b = blockIdx.y;
    __shared__ unsigned cnt[NWORD8];  // 50 KB
    for (int i = threadIdx.x; i < NWORD8; i += 1024) cnt[i] = 0;
    __syncthreads();
    const int4* __restrict__ dst4 =
        (const int4*)(ei + (size_t)b * (2 * N_EDGES) + N_EDGES) + (size_t)chunk * HEPC4;
    for (int i = threadIdx.x; i < HEPC4; i += 1024) {
        const int4 v = dst4[i];
        atomicAdd(&cnt[((unsigned)v.x) >> 2], 1u << ((v.x & 3) * 8));
        atomicAdd(&cnt[((unsigned)v.y) >> 2], 1u << ((v.y & 3) * 8));
        atomicAdd(&cnt[((unsigned)v.z) >> 2], 1u << ((v.z & 3) * 8));
        atomicAdd(&cnt[((unsigned)v.w) >> 2], 1u << ((v.w & 3) * 8));
    }
    __syncthreads();
    unsigned* __restrict__ out = partials + (size_t)(b * HCHUNKS + chunk) * NWORD8;
    for (int i = threadIdx.x; i < NWORD8; i += 1024) out[i] = cnt[i];
}

// ---------------------------------------------------------------------------
// K2: reduce degree partials -> dinv[b][n] = rsqrt(count+1) (f32)
//     and qd8 = round(dinv * 255) packed x4 per u32 (LDS gather table for K3).
//     Also zeroes the pool done-counter for K4's last-block MLP.
// ---------------------------------------------------------------------------
__global__ void dinv_kernel(const unsigned* __restrict__ partials,
                            float* __restrict__ dinv,
                            unsigned* __restrict__ qd8,
                            unsigned* __restrict__ done) {
    const int idx = blockIdx.x * 256 + threadIdx.x;
    if (idx == 0) *done = 0u;   // re-zero each iteration (ws is poisoned)
    if (idx >= BATCH * NWORD8) return;
    const int b = idx / NWORD8, i = idx - b * NWORD8;
    const unsigned* __restrict__ p = partials + (size_t)(b * HCHUNKS) * NWORD8 + i;
    unsigned d0 = 0, d1 = 0, d2 = 0, d3 = 0;
#pragma unroll
    for (int c = 0; c < HCHUNKS; ++c) {
        const unsigned v = p[(size_t)c * NWORD8];
        d0 += v & 0xFF; d1 += (v >> 8) & 0xFF; d2 += (v >> 16) & 0xFF; d3 += v >> 24;
    }
    const float i0 = rsqrtf((float)(d0 + 1));
    const float i1 = rsqrtf((float)(d1 + 1));
    const float i2 = rsqrtf((float)(d2 + 1));
    const float i3 = rsqrtf((float)(d3 + 1));
    float4* dv4 = (float4*)(dinv + (size_t)b * N_NODES) + i;
    *dv4 = make_float4(i0, i1, i2, i3);
    const unsigned q0 = __float2uint_rn(i0 * QSCALE);
    const unsigned q1 = __float2uint_rn(i1 * QSCALE);
    const unsigned q2 = __float2uint_rn(i2 * QSCALE);
    const unsigned q3 = __float2uint_rn(i3 * QSCALE);
    qd8[(size_t)b * NWORD8 + i] = q0 | (q1 << 8) | (q2 << 16) | (q3 << 24);
}

// ---------------------------------------------------------------------------
// K3: c[n] = sum over out-edges of n of dinv[dst], u16 fixed-point histogram
// over the FULL node range. dst-side dinv table lives in LDS as u8 (50 KB).
// Dynamic LDS = 100 KB histogram + 50 KB qd8 = 150 KB; 256 blocks = 1/CU.
// ---------------------------------------------------------------------------
__global__ __launch_bounds__(1024) void cscat_kernel(const int* __restrict__ ei,
                                                     const unsigned* __restrict__ qd8,
                                                     unsigned* __restrict__ cpart) {
    extern __shared__ unsigned smem[];           // [0,25000): cs, [25000,37500): qd8
    unsigned* cs = smem;
    const unsigned char* qs = (const unsigned char*)(smem + NWORDC);
    const int id = blockIdx.x;  // 256 = 8 xcd * 4 bgroup * 8 chunk
    const int b = (id & 7) + 8 * ((id >> 3) & 3);
    const int chunk = id >> 5;
    for (int i = threadIdx.x; i < NWORDC; i += 1024) cs[i] = 0;
    {   // stage the batch's u8 dinv table into LDS (coalesced, 50 KB)
        const unsigned* __restrict__ src = qd8 + (size_t)b * NWORD8;
        unsigned* dst = smem + NWORDC;
        for (int i = threadIdx.x; i < NWORD8; i += 1024) dst[i] = src[i];
    }
    __syncthreads();
    const int* eb = ei + (size_t)b * (2 * N_EDGES);
    const int4* __restrict__ src4 = (const int4*)eb + (size_t)chunk * EPC4;
    const int4* __restrict__ dst4 = (const int4*)(eb + N_EDGES) + (size_t)chunk * EPC4;
    for (int i = threadIdx.x; i < EPC4; i += 1024) {
        const int4 s4 = src4[i];
        const int4 d4 = dst4[i];
        const unsigned q0 = qs[d4.x];
        const unsigned q1 = qs[d4.y];
        const unsigned q2 = qs[d4.z];
        const unsigned q3 = qs[d4.w];
        atomicAdd(&cs[((unsigned)s4.x) >> 1], q0 << ((s4.x & 1) << 4));
        atomicAdd(&cs[((unsigned)s4.y) >> 1], q1 << ((s4.y & 1) << 4));
        atomicAdd(&cs[((unsigned)s4.z) >> 1], q2 << ((s4.z & 1) << 4));
        atomicAdd(&cs[((unsigned)s4.w) >> 1], q3 << ((s4.w & 1) << 4));
    }
    __syncthreads();
    unsigned* __restrict__ out = cpart + (size_t)(b * CHUNKS + chunk) * NWORDC;
    for (int i = threadIdx.x; i < NWORDC; i += 1024) out[i] = cs[i];
}

// ---------------------------------------------------------------------------
// K4: fused w + pool + (last block) MLP.
//  - per-block w-slice: reduce 8 cpart chunks for 3125 words -> wlds in LDS
//    (folds old K4: removes 6.4 MB w write + 6.4 MB read + global w gather)
//  - pooled weighted column-sum over the slice (float4, fixed channel phase)
//  - last-arriving block (threadfence + done-counter) reduces spart and runs
//    the tiny MLP + log_softmax (folds old K6; saves a full-device round trip)
// ---------------------------------------------------------------------------
__global__ __launch_bounds__(1024) void poolw_kernel(
    const unsigned* __restrict__ cpart, const float* __restrict__ dinv,
    const float* __restrict__ xg, const float* __restrict__ x,
    const float* __restrict__ W_gcn, const float* __restrict__ b_gcn,
    const float* __restrict__ W1, const float* __restrict__ b1,
    const float* __restrict__ W2, const float* __restrict__ b2,
    const float* __restrict__ Wo, const float* __restrict__ bo,
    float* __restrict__ spart, unsigned* __restrict__ done,
    float* __restrict__ out)
{
    __shared__ float smf[8768];    // pool: wlds[6250]+sacc@6256[160]; MLP reuses
    __shared__ unsigned lastf;
    const int c = blockIdx.x, b = blockIdx.y;   // grid (8, 32)
    const int tid = threadIdx.x;
    float* wlds = smf;
    float* sacc = smf + 6256;

    // ---- w-slice: w[n] = dinv*(c+dinv) for this block's 6250 nodes ----
    const int wbase = c * (NWORDC / 8);          // 3125 u16-pair words
    for (int i = tid; i < NWORDC / 8; i += 1024) {
        const unsigned* __restrict__ p =
            cpart + (size_t)(b * CHUNKS) * NWORDC + wbase + i;
        unsigned c0 = 0, c1 = 0;
#pragma unroll
        for (int ch = 0; ch < CHUNKS; ++ch) {
            const unsigned v = p[(size_t)ch * NWORDC];
            c0 += v & 0xFFFF; c1 += v >> 16;
        }
        const int node = 2 * (wbase + i);
        const float2 d = *((const float2*)(dinv + (size_t)b * N_NODES + node));
        wlds[2 * i]     = d.x * ((float)c0 * (1.0f / QSCALE) + d.x);
        wlds[2 * i + 1] = d.y * ((float)c1 * (1.0f / QSCALE) + d.y);
    }
    const int wave = tid >> 6;
    if ((tid & 63) < 10) sacc[wave * 10 + (tid & 63)] = 0.0f;
    __syncthreads();

    // ---- pooled weighted column-sum (verified in round-1 mega P4) ----
    if (tid < ACTIVE) {
        const float4* __restrict__ xg4 = (const float4*)xg;
        const int base4 = b * 125000 + c * 15625;  // 4*base4 % 10 == 0
        const int r = (4 * tid) % 10;              // channel phase, fixed per lane
        float a0 = 0.0f, a1 = 0.0f, a2 = 0.0f, a3 = 0.0f;
        for (int j = tid; j < 15625; j += ACTIVE) {
            const float4 v = xg4[base4 + j];
            const int ln = (4 * j) / 10;           // local node in [0,6250)
            const float w0 = wlds[ln];
            const float w1 = (r == 8) ? wlds[ln + 1] : w0;  // r==8: z,w cross node
            a0 += v.x * w0;
            a1 += v.y * w0;
            a2 += v.z * w1;
            a3 += v.w * w1;
        }
        atomicAdd(&sacc[wave * 10 + r], a0);
        atomicAdd(&sacc[wave * 10 + (r + 1) % 10], a1);
        atomicAdd(&sacc[wave * 10 + (r + 2) % 10], a2);
        atomicAdd(&sacc[wave * 10 + (r + 3) % 10], a3);
    }
    __syncthreads();
    if (tid < 10) {
        float v = 0.0f;
#pragma unroll
        for (int wv = 0; wv < 16; ++wv) v += sacc[wv * 10 + tid];
        spart[(b * CHUNKS + c) * 16 + tid] = v;
    }

    // ---- last-block fan-in (threadfence reduction pattern) ----
    __threadfence();                 // publish this block's spart device-wide
    __syncthreads();
    if (tid == 0) lastf = (atomicAdd(done, 1u) == (unsigned)(8 * BATCH - 1));
    __syncthreads();
    if (!lastf) return;
    __threadfence();                 // acquire: see all blocks' spart

    // ---- tiny MLP + log_softmax(axis=0), one block, smf reused ----
    float* ssum = smf;           // [32][10]
    float* h0   = smf + 320;     // [32][20]
    float* h1   = smf + 960;     // [32][80]
    float* h2   = smf + 3520;    // [32][160]
    float* o    = smf + 8640;    // [32][4]

    for (int idx = tid; idx < 32 * 10; idx += 1024) {
        const int bb = idx / 10, k = idx % 10;
        float v = 0.0f;
#pragma unroll
        for (int ch = 0; ch < CHUNKS; ++ch) v += spart[(bb * CHUNKS + ch) * 16 + k];
        ssum[bb * 10 + k] = v;
    }
    __syncthreads();

    for (int idx = tid; idx < 32 * 20; idx += 1024) {
        const int bb = idx / 20, j = idx % 20;
        float v;
        if (j < 10) {
            v = 0.0f;
#pragma unroll
            for (int k = 0; k < 10; ++k) v += ssum[bb * 10 + k] * W_gcn[k * 10 + j];
            v = v * (1.0f / (float)N_NODES) + b_gcn[j];
        } else {
            v = x[bb * 10 + (j - 10)];
        }
        h0[bb * 20 + j] = v;
    }
    __syncthreads();

    for (int idx = tid; idx < 32 * 80; idx += 1024) {
        const int bb = idx / 80, j = idx % 80;
        float v = b1[j];
#pragma unroll
        for (int k = 0; k < 20; ++k) v += h0[bb * 20 + k] * W1[k * 80 + j];
        h1[bb * 80 + j] = (v > 0.0f) ? v : 0.01f * v;
    }
    __syncthreads();

    for (int idx = tid; idx < 32 * 160; idx += 1024) {
        const int bb = idx / 160, j = idx % 160;
        float v = b2[j];
        for (int k = 0; k < 80; ++k) v += h1[bb * 80 + k] * W2[k * 160 + j];
        h2[bb * 160 + j] = (v > 0.0f) ? v : 0.01f * v;
    }
    __syncthreads();

    for (int idx = tid; idx < 32 * 4; idx += 1024) {
        const int bb = idx / 4, j = idx % 4;
        float v = bo[j];
        for (int k = 0; k < 160; ++k) v += h2[bb * 160 + k] * Wo[k * 4 + j];
        o[bb * 4 + j] = v;
    }
    __syncthreads();

    if (tid < 4) {
        float m = -1e30f;
        for (int bb = 0; bb < 32; ++bb) m = fmaxf(m, o[bb * 4 + tid]);
        float lse = 0.0f;
        for (int bb = 0; bb < 32; ++bb) lse += expf(o[bb * 4 + tid] - m);
        lse = logf(lse);
        for (int bb = 0; bb < 32; ++bb) out[bb * 4 + tid] = o[bb * 4 + tid] - m - lse;
    }
}

extern "C" void kernel_launch(void* const* d_in, const int* in_sizes, int n_in,
                              void* d_out, int out_size, void* d_ws, size_t ws_size,
                              hipStream_t stream) {
    (void)in_sizes; (void)n_in; (void)out_size; (void)ws_size;
    const float* x      = (const float*)d_in[0];
    const float* gcn_x  = (const float*)d_in[1];
    const int*   ei     = (const int*)d_in[2];
    const float* W_gcn  = (const float*)d_in[3];
    const float* b_gcn  = (const float*)d_in[4];
    const float* W1     = (const float*)d_in[5];
    const float* b1     = (const float*)d_in[6];
    const float* W2     = (const float*)d_in[7];
    const float* b2     = (const float*)d_in[8];
    const float* Wo     = (const float*)d_in[9];
    const float* bo     = (const float*)d_in[10];
    float* out = (float*)d_out;

    // workspace layout (offsets in bytes):
    //   partials [512*12500 u32]        @ 0          (25.6 MB; hist 16-chunk / cscat 8-chunk reuse)
    //   dinv     [32*50000 f32]         @ 25,600,000 (6.4 MB)
    //   qd8      [32*12500 u32 packed]  @ 32,000,000 (1.6 MB)
    //   spart    [32*8*16 f32]          @ 33,600,000 (16 KB)
    //   done     [1 u32]                @ 33,616,384
    unsigned* partials = (unsigned*)d_ws;
    float*    dinv     = (float*)((char*)d_ws + (size_t)512 * NWORD8 * 4);
    unsigned* qd8      = (unsigned*)((char*)dinv + (size_t)BATCH * N_NODES * 4);
    float*    spart    = (float*)((char*)qd8 + (size_t)BATCH * NWORD8 * 4);
    unsigned* done     = (unsigned*)((char*)spart + (size_t)BATCH * CHUNKS * 16 * 4);

    // 150 KB dynamic LDS for c-histogram (100 KB) + u8 dinv table (50 KB).
    // One-time host-side attribute set (kept out of repeated graph captures).
    static bool attr_set = false;
    if (!attr_set) {
        hipFuncSetAttribute((const void*)cscat_kernel,
                            hipFuncAttributeMaxDynamicSharedMemorySize,
                            (NWORDC + NWORD8) * 4);
        attr_set = true;
    }

    {   // K1: degree histograms (512 blocks -> 2/CU)
        dim3 grid(HCHUNKS, BATCH);
        hist_kernel<<<grid, 1024, 0, stream>>>(ei, partials);
    }
    {   // K2: reduce -> dinv (f32), qd8 (u8 packed); zero done-counter
        const int n = BATCH * NWORD8;
        dinv_kernel<<<(n + 255) / 256, 256, 0, stream>>>(partials, dinv, qd8, done);
    }
    {   // K3: full-range c-scatter, LDS-resident gather table (150 KB LDS)
        cscat_kernel<<<256, 1024, (NWORDC + NWORD8) * 4, stream>>>(ei, qd8, partials);
    }
    {   // K4: fused w + pool + last-block MLP (256 blocks -> 1/CU)
        dim3 grid(CHUNKS, BATCH);
        poolw_kernel<<<grid, 1024, 0, stream>>>(partials, dinv, gcn_x, x,
                                                W_gcn, b_gcn, W1, b1, W2, b2, Wo, bo,
                                                spart, done, out);
    }
}

// Round 4
// 404.949 us; speedup vs baseline: 2.2203x; 1.1301x over previous
//
#include <hip/hip_runtime.h>

#define N_NODES 50000
#define N_EDGES 800000
#define BATCH   32
#define NWORD8  12500   // N_NODES/4 u32 words (u8-packed deg counts / qd8 table)
#define NWORDC  25000   // N_NODES/2 u32 words, u16-packed c (full range, 100 KB)
#define CHUNKS  8       // edge chunks for hist AND cscat (100K edges each)
#define EPC4    25000   // int4 edge loads per chunk (= 100000 edges)
#define QSCALE  255.0f
#define PTHREADS 640    // pool threads: 640*4 % 10 == 0 keeps per-lane phase const

// ---------------------------------------------------------------------------
// K1: per-(batch,chunk) degree histogram in LDS (u8 packed x4 per u32 word).
// 8 chunks of 100K edges -> 256 blocks -> 1/CU. Per-chunk degree is
// Binomial(100K, 1/50K): mean 2, P(>255) ~ 0 -> u8 packing safe.
// Halves partial traffic vs 16-chunk variant (12.8 MB vs 25.6 MB).
// ---------------------------------------------------------------------------
__global__ __launch_bounds__(1024) void hist_kernel(const int* __restrict__ ei,
                                                    unsigned* __restrict__ partials) {
    const int chunk = blockIdx.x, b = blockIdx.y;   // grid (8, 32)
    __shared__ unsigned cnt[NWORD8];  // 50 KB
    for (int i = threadIdx.x; i < NWORD8; i += 1024) cnt[i] = 0;
    __syncthreads();
    const int4* __restrict__ dst4 =
        (const int4*)(ei + (size_t)b * (2 * N_EDGES) + N_EDGES) + (size_t)chunk * EPC4;
    for (int i = threadIdx.x; i < EPC4; i += 1024) {
        const int4 v = dst4[i];
        atomicAdd(&cnt[((unsigned)v.x) >> 2], 1u << ((v.x & 3) * 8));
        atomicAdd(&cnt[((unsigned)v.y) >> 2], 1u << ((v.y & 3) * 8));
        atomicAdd(&cnt[((unsigned)v.z) >> 2], 1u << ((v.z & 3) * 8));
        atomicAdd(&cnt[((unsigned)v.w) >> 2], 1u << ((v.w & 3) * 8));
    }
    __syncthreads();
    unsigned* __restrict__ out = partials + (size_t)(b * CHUNKS + chunk) * NWORD8;
    for (int i = threadIdx.x; i < NWORD8; i += 1024) out[i] = cnt[i];
}

// ---------------------------------------------------------------------------
// K2: reduce degree partials -> dinv[b][n] = rsqrt(count+1) (f32)
//     and qd8 = round(dinv * 255) packed x4 per u32 (LDS gather table for K3).
// ---------------------------------------------------------------------------
__global__ void dinv_kernel(const unsigned* __restrict__ partials,
                            float* __restrict__ dinv,
                            unsigned* __restrict__ qd8) {
    const int idx = blockIdx.x * 256 + threadIdx.x;
    if (idx >= BATCH * NWORD8) return;
    const int b = idx / NWORD8, i = idx - b * NWORD8;
    const unsigned* __restrict__ p = partials + (size_t)(b * CHUNKS) * NWORD8 + i;
    unsigned d0 = 0, d1 = 0, d2 = 0, d3 = 0;
#pragma unroll
    for (int c = 0; c < CHUNKS; ++c) {
        const unsigned v = p[(size_t)c * NWORD8];
        d0 += v & 0xFF; d1 += (v >> 8) & 0xFF; d2 += (v >> 16) & 0xFF; d3 += v >> 24;
    }
    const float i0 = rsqrtf((float)(d0 + 1));
    const float i1 = rsqrtf((float)(d1 + 1));
    const float i2 = rsqrtf((float)(d2 + 1));
    const float i3 = rsqrtf((float)(d3 + 1));
    float4* dv4 = (float4*)(dinv + (size_t)b * N_NODES) + i;
    *dv4 = make_float4(i0, i1, i2, i3);
    const unsigned q0 = __float2uint_rn(i0 * QSCALE);
    const unsigned q1 = __float2uint_rn(i1 * QSCALE);
    const unsigned q2 = __float2uint_rn(i2 * QSCALE);
    const unsigned q3 = __float2uint_rn(i3 * QSCALE);
    qd8[(size_t)b * NWORD8 + i] = q0 | (q1 << 8) | (q2 << 16) | (q3 << 24);
}

// ---------------------------------------------------------------------------
// K3: c[n] = sum over out-edges of n of dinv[dst], u16 fixed-point histogram
// over the FULL node range. dst-side dinv table lives in LDS as u8 (50 KB):
// the random gather is a ds_read_u8, not a divergent global load.
// Dynamic LDS = 100 KB histogram + 50 KB qd8 = 150 KB; 256 blocks = 1/CU.
// ---------------------------------------------------------------------------
__global__ __launch_bounds__(1024) void cscat_kernel(const int* __restrict__ ei,
                                                     const unsigned* __restrict__ qd8,
                                                     unsigned* __restrict__ cpart) {
    extern __shared__ unsigned smem[];           // [0,25000): cs, [25000,37500): qd8
    unsigned* cs = smem;
    const unsigned char* qs = (const unsigned char*)(smem + NWORDC);
    const int id = blockIdx.x;  // 256 = 8 xcd * 4 bgroup * 8 chunk
    const int b = (id & 7) + 8 * ((id >> 3) & 3);
    const int chunk = id >> 5;
    for (int i = threadIdx.x; i < NWORDC; i += 1024) cs[i] = 0;
    {   // stage the batch's u8 dinv table into LDS (coalesced, 50 KB)
        const unsigned* __restrict__ src = qd8 + (size_t)b * NWORD8;
        unsigned* dst = smem + NWORDC;
        for (int i = threadIdx.x; i < NWORD8; i += 1024) dst[i] = src[i];
    }
    __syncthreads();
    const int* eb = ei + (size_t)b * (2 * N_EDGES);
    const int4* __restrict__ src4 = (const int4*)eb + (size_t)chunk * EPC4;
    const int4* __restrict__ dst4 = (const int4*)(eb + N_EDGES) + (size_t)chunk * EPC4;
    for (int i = threadIdx.x; i < EPC4; i += 1024) {
        const int4 s4 = src4[i];
        const int4 d4 = dst4[i];
        const unsigned q0 = qs[d4.x];
        const unsigned q1 = qs[d4.y];
        const unsigned q2 = qs[d4.z];
        const unsigned q3 = qs[d4.w];
        atomicAdd(&cs[((unsigned)s4.x) >> 1], q0 << ((s4.x & 1) << 4));
        atomicAdd(&cs[((unsigned)s4.y) >> 1], q1 << ((s4.y & 1) << 4));
        atomicAdd(&cs[((unsigned)s4.z) >> 1], q2 << ((s4.z & 1) << 4));
        atomicAdd(&cs[((unsigned)s4.w) >> 1], q3 << ((s4.w & 1) << 4));
    }
    __syncthreads();
    unsigned* __restrict__ out = cpart + (size_t)(b * CHUNKS + chunk) * NWORDC;
    for (int i = threadIdx.x; i < NWORDC; i += 1024) out[i] = cs[i];
}

// ---------------------------------------------------------------------------
// K4: w[b][n] = dinv * (c + dinv)   (the +dinv folds the self-loop dinv^2)
// ---------------------------------------------------------------------------
__global__ void w_kernel(const unsigned* __restrict__ cpart,
                         const float* __restrict__ dinv,
                         float* __restrict__ w) {
    const int idx = blockIdx.x * 256 + threadIdx.x;
    if (idx >= BATCH * NWORDC) return;
    const int b = idx / NWORDC, i = idx - b * NWORDC;
    const unsigned* __restrict__ p = cpart + (size_t)(b * CHUNKS) * NWORDC + i;
    unsigned c0 = 0, c1 = 0;
#pragma unroll
    for (int c = 0; c < CHUNKS; ++c) {
        const unsigned v = p[(size_t)c * NWORDC];
        c0 += v & 0xFFFF; c1 += v >> 16;
    }
    const int node = 2 * i;
    const float2 d = *((const float2*)(dinv + (size_t)b * N_NODES + node));
    const float f0 = (float)c0 * (1.0f / QSCALE);
    const float f1 = (float)c1 * (1.0f / QSCALE);
    *((float2*)(w + (size_t)b * N_NODES + node)) = make_float2(d.x * (f0 + d.x), d.y * (f1 + d.y));
}

// ---------------------------------------------------------------------------
// K5: pooled weighted column-sum, float4 coalesced. 640 threads (10 waves/CU).
// 640*4 % 10 == 0 -> per-lane channel phase is loop-invariant. Per-wave LDS
// accumulator rows (low contention), then per-block partials (no global atomics).
// ---------------------------------------------------------------------------
__global__ __launch_bounds__(PTHREADS) void pool_kernel(const float* __restrict__ xg,
                                                        const float* __restrict__ w,
                                                        float* __restrict__ spart) {
    const int chunk = blockIdx.x, b = blockIdx.y;  // grid (8, 32)
    const float4* __restrict__ xg4 = (const float4*)xg;
    const int base4 = b * 125000 + chunk * 15625;  // float4 index; 4*base4 % 10 == 0
    const int r = (4 * threadIdx.x) % 10;          // element phase, fixed per lane
    float a0 = 0.0f, a1 = 0.0f, a2 = 0.0f, a3 = 0.0f;
    for (int j = threadIdx.x; j < 15625; j += PTHREADS) {
        const int f4 = base4 + j;
        const int e0 = f4 * 4;             // global element idx; w idx = e0/10
        const float4 v = xg4[f4];
        const float w0 = w[e0 / 10];
        const float w1 = (r == 8) ? w[e0 / 10 + 1] : w0;  // r==8: z,w cross node boundary
        a0 += v.x * w0;
        a1 += v.y * w0;
        a2 += v.z * w1;
        a3 += v.w * w1;
    }
    __shared__ float sacc[PTHREADS / 64][10];
    const int wave = threadIdx.x >> 6;
    if ((threadIdx.x & 63) < 10) sacc[wave][threadIdx.x & 63] = 0.0f;
    __syncthreads();
    atomicAdd(&sacc[wave][r], a0);
    atomicAdd(&sacc[wave][(r + 1) % 10], a1);
    atomicAdd(&sacc[wave][(r + 2) % 10], a2);
    atomicAdd(&sacc[wave][(r + 3) % 10], a3);
    __syncthreads();
    if (threadIdx.x < 10) {
        float v = 0.0f;
#pragma unroll
        for (int wv = 0; wv < PTHREADS / 64; ++wv) v += sacc[wv][threadIdx.x];
        spart[(b * CHUNKS + chunk) * 16 + threadIdx.x] = v;
    }
}

// ---------------------------------------------------------------------------
// K6: reduce pool partials + tiny MLP + log_softmax(axis=0). One block.
// ---------------------------------------------------------------------------
__global__ __launch_bounds__(512) void mlp_kernel(const float* __restrict__ spart,
                           const float* __restrict__ x,
                           const float* __restrict__ W_gcn,
                           const float* __restrict__ b_gcn,
                           const float* __restrict__ W1, const float* __restrict__ b1,
                           const float* __restrict__ W2, const float* __restrict__ b2,
                           const float* __restrict__ Wo, const float* __restrict__ bo,
                           float* __restrict__ out) {
    __shared__ float ssum[32][10];
    __shared__ float h0[32][20];
    __shared__ float h1[32][80];
    __shared__ float h2[32][160];
    __shared__ float o[32][4];
    const int tid = threadIdx.x;

    for (int idx = tid; idx < 32 * 10; idx += blockDim.x) {
        const int b = idx / 10, k = idx % 10;
        float v = 0.0f;
#pragma unroll
        for (int c = 0; c < CHUNKS; ++c) v += spart[(b * CHUNKS + c) * 16 + k];
        ssum[b][k] = v;
    }
    __syncthreads();

    for (int idx = tid; idx < 32 * 20; idx += blockDim.x) {
        const int b = idx / 20, j = idx % 20;
        float v;
        if (j < 10) {
            v = 0.0f;
#pragma unroll
            for (int k = 0; k < 10; ++k) v += ssum[b][k] * W_gcn[k * 10 + j];
            v = v * (1.0f / (float)N_NODES) + b_gcn[j];
        } else {
            v = x[b * 10 + (j - 10)];
        }
        h0[b][j] = v;
    }
    __syncthreads();

    for (int idx = tid; idx < 32 * 80; idx += blockDim.x) {
        const int b = idx / 80, j = idx % 80;
        float v = b1[j];
#pragma unroll
        for (int k = 0; k < 20; ++k) v += h0[b][k] * W1[k * 80 + j];
        h1[b][j] = (v > 0.0f) ? v : 0.01f * v;
    }
    __syncthreads();

    for (int idx = tid; idx < 32 * 160; idx += blockDim.x) {
        const int b = idx / 160, j = idx % 160;
        float v = b2[j];
        for (int k = 0; k < 80; ++k) v += h1[b][k] * W2[k * 160 + j];
        h2[b][j] = (v > 0.0f) ? v : 0.01f * v;
    }
    __syncthreads();

    for (int idx = tid; idx < 32 * 4; idx += blockDim.x) {
        const int b = idx / 4, j = idx % 4;
        float v = bo[j];
        for (int k = 0; k < 160; ++k) v += h2[b][k] * Wo[k * 4 + j];
        o[b][j] = v;
    }
    __syncthreads();

    if (tid < 4) {
        float m = -1e30f;
        for (int b = 0; b < 32; ++b) m = fmaxf(m, o[b][tid]);
        float lse = 0.0f;
        for (int b = 0; b < 32; ++b) lse += expf(o[b][tid] - m);
        lse = logf(lse);
        for (int b = 0; b < 32; ++b) out[b * 4 + tid] = o[b][tid] - m - lse;
    }
}

extern "C" void kernel_launch(void* const* d_in, const int* in_sizes, int n_in,
                              void* d_out, int out_size, void* d_ws, size_t ws_size,
                              hipStream_t stream) {
    (void)in_sizes; (void)n_in; (void)out_size; (void)ws_size;
    const float* x      = (const float*)d_in[0];
    const float* gcn_x  = (const float*)d_in[1];
    const int*   ei     = (const int*)d_in[2];
    const float* W_gcn  = (const float*)d_in[3];
    const float* b_gcn  = (const float*)d_in[4];
    const float* W1     = (const float*)d_in[5];
    const float* b1     = (const float*)d_in[6];
    const float* W2     = (const float*)d_in[7];
    const float* b2     = (const float*)d_in[8];
    const float* Wo     = (const float*)d_in[9];
    const float* bo     = (const float*)d_in[10];
    float* out = (float*)d_out;

    // workspace layout (offsets in bytes):
    //   partials region [25.6 MB] @ 0     (hist uses 12.8 MB of it; cscat 25.6 MB)
    //   dinv     [32*50000 f32]   @ 25,600,000 (6.4 MB)
    //   qd8      [32*12500 u32]   @ 32,000,000 (1.6 MB)
    //   w        [32*50000 f32]   @ 33,600,000 (6.4 MB)
    //   spart    [32*8*16 f32]    @ 40,000,000 (16 KB)    total ~40 MB
    unsigned* partials = (unsigned*)d_ws;
    float*    dinv     = (float*)((char*)d_ws + (size_t)BATCH * CHUNKS * NWORDC * 4);
    unsigned* qd8      = (unsigned*)((char*)dinv + (size_t)BATCH * N_NODES * 4);
    float*    w        = (float*)((char*)qd8 + (size_t)BATCH * NWORD8 * 4);
    float*    spart    = (float*)((char*)w + (size_t)BATCH * N_NODES * 4);

    // 150 KB dynamic LDS for c-histogram (100 KB) + u8 dinv table (50 KB)
    hipFuncSetAttribute((const void*)cscat_kernel,
                        hipFuncAttributeMaxDynamicSharedMemorySize,
                        (NWORDC + NWORD8) * 4);

    {   // K1: degree histograms (8 chunks, 256 blocks -> 1/CU)
        dim3 grid(CHUNKS, BATCH);
        hist_kernel<<<grid, 1024, 0, stream>>>(ei, partials);
    }
    {   // K2: reduce -> dinv (f32), qd8 (u8 packed)
        const int n = BATCH * NWORD8;
        dinv_kernel<<<(n + 255) / 256, 256, 0, stream>>>(partials, dinv, qd8);
    }
    {   // K3: full-range c-scatter, LDS-resident gather table (150 KB LDS)
        cscat_kernel<<<256, 1024, (NWORDC + NWORD8) * 4, stream>>>(ei, qd8, partials);
    }
    {   // K4: w = dinv*(c+dinv)
        const int n = BATCH * NWORDC;
        w_kernel<<<(n + 255) / 256, 256, 0, stream>>>(partials, dinv, w);
    }
    {   // K5: pooled weighted column-sum (float4, 10 waves/CU, no atomics)
        dim3 grid(CHUNKS, BATCH);
        pool_kernel<<<grid, PTHREADS, 0, stream>>>(gcn_x, w, spart);
    }
    mlp_kernel<<<1, 512, 0, stream>>>(spart, x, W_gcn, b_gcn, W1, b1, W2, b2, Wo, bo, out);
}

// Round 5
// 397.728 us; speedup vs baseline: 2.2606x; 1.0182x over previous
//
#include <hip/hip_runtime.h>

#define N_NODES 50000
#define N_EDGES 800000
#define BATCH   32
#define NWORD8  12500   // N_NODES/4 u32 words (u8-packed deg counts / qd8 table)
#define NWORDC  25000   // N_NODES/2 u32 words, u16-packed c (full range, 100 KB)
#define CHUNKS  8       // edge chunks for hist AND cscat (100K edges each)
#define EPC4    25000   // int4 edge loads per chunk (= 100000 edges)
#define QSCALE  255.0f
#define PTHREADS 640    // pool threads: 640*4 % 10 == 0 keeps per-lane phase const

// ---------------------------------------------------------------------------
// K1: per-(batch,chunk) degree histogram in LDS (u8 packed x4 per u32 word).
// 8 chunks of 100K edges -> 256 blocks -> 1/CU. Per-chunk degree is
// Binomial(100K, 1/50K): mean 2, P(>255) ~ 0 -> u8 packing safe.
// ---------------------------------------------------------------------------
__global__ __launch_bounds__(1024) void hist_kernel(const int* __restrict__ ei,
                                                    unsigned* __restrict__ partials) {
    const int chunk = blockIdx.x, b = blockIdx.y;   // grid (8, 32)
    __shared__ unsigned cnt[NWORD8];  // 50 KB
    for (int i = threadIdx.x; i < NWORD8; i += 1024) cnt[i] = 0;
    __syncthreads();
    const int4* __restrict__ dst4 =
        (const int4*)(ei + (size_t)b * (2 * N_EDGES) + N_EDGES) + (size_t)chunk * EPC4;
    for (int i = threadIdx.x; i < EPC4; i += 1024) {
        const int4 v = dst4[i];
        atomicAdd(&cnt[((unsigned)v.x) >> 2], 1u << ((v.x & 3) * 8));
        atomicAdd(&cnt[((unsigned)v.y) >> 2], 1u << ((v.y & 3) * 8));
        atomicAdd(&cnt[((unsigned)v.z) >> 2], 1u << ((v.z & 3) * 8));
        atomicAdd(&cnt[((unsigned)v.w) >> 2], 1u << ((v.w & 3) * 8));
    }
    __syncthreads();
    unsigned* __restrict__ out = partials + (size_t)(b * CHUNKS + chunk) * NWORD8;
    for (int i = threadIdx.x; i < NWORD8; i += 1024) out[i] = cnt[i];
}

// ---------------------------------------------------------------------------
// K2: reduce degree partials -> dinv[b][n] = rsqrt(count+1) (f32)
//     and qd8 = round(dinv * 255) packed x4 per u32 (LDS gather table for K3).
// ---------------------------------------------------------------------------
__global__ void dinv_kernel(const unsigned* __restrict__ partials,
                            float* __restrict__ dinv,
                            unsigned* __restrict__ qd8) {
    const int idx = blockIdx.x * 256 + threadIdx.x;
    if (idx >= BATCH * NWORD8) return;
    const int b = idx / NWORD8, i = idx - b * NWORD8;
    const unsigned* __restrict__ p = partials + (size_t)(b * CHUNKS) * NWORD8 + i;
    unsigned d0 = 0, d1 = 0, d2 = 0, d3 = 0;
#pragma unroll
    for (int c = 0; c < CHUNKS; ++c) {
        const unsigned v = p[(size_t)c * NWORD8];
        d0 += v & 0xFF; d1 += (v >> 8) & 0xFF; d2 += (v >> 16) & 0xFF; d3 += v >> 24;
    }
    const float i0 = rsqrtf((float)(d0 + 1));
    const float i1 = rsqrtf((float)(d1 + 1));
    const float i2 = rsqrtf((float)(d2 + 1));
    const float i3 = rsqrtf((float)(d3 + 1));
    float4* dv4 = (float4*)(dinv + (size_t)b * N_NODES) + i;
    *dv4 = make_float4(i0, i1, i2, i3);
    const unsigned q0 = __float2uint_rn(i0 * QSCALE);
    const unsigned q1 = __float2uint_rn(i1 * QSCALE);
    const unsigned q2 = __float2uint_rn(i2 * QSCALE);
    const unsigned q3 = __float2uint_rn(i3 * QSCALE);
    qd8[(size_t)b * NWORD8 + i] = q0 | (q1 << 8) | (q2 << 16) | (q3 << 24);
}

// ---------------------------------------------------------------------------
// K3: c[n] = sum over out-edges of n of dinv[dst], u16 fixed-point histogram
// over the FULL node range. dst-side dinv table lives in LDS as u8 (50 KB):
// the random gather is a ds_read_u8, not a divergent global load.
// Dynamic LDS = 100 KB histogram + 50 KB qd8 = 150 KB; 256 blocks = 1/CU.
// ---------------------------------------------------------------------------
__global__ __launch_bounds__(1024) void cscat_kernel(const int* __restrict__ ei,
                                                     const unsigned* __restrict__ qd8,
                                                     unsigned* __restrict__ cpart) {
    extern __shared__ unsigned smem[];           // [0,25000): cs, [25000,37500): qd8
    unsigned* cs = smem;
    const unsigned char* qs = (const unsigned char*)(smem + NWORDC);
    const int id = blockIdx.x;  // 256 = 8 xcd * 4 bgroup * 8 chunk
    const int b = (id & 7) + 8 * ((id >> 3) & 3);
    const int chunk = id >> 5;
    for (int i = threadIdx.x; i < NWORDC; i += 1024) cs[i] = 0;
    {   // stage the batch's u8 dinv table into LDS (coalesced, 50 KB)
        const unsigned* __restrict__ src = qd8 + (size_t)b * NWORD8;
        unsigned* dst = smem + NWORDC;
        for (int i = threadIdx.x; i < NWORD8; i += 1024) dst[i] = src[i];
    }
    __syncthreads();
    const int* eb = ei + (size_t)b * (2 * N_EDGES);
    const int4* __restrict__ src4 = (const int4*)eb + (size_t)chunk * EPC4;
    const int4* __restrict__ dst4 = (const int4*)(eb + N_EDGES) + (size_t)chunk * EPC4;
    for (int i = threadIdx.x; i < EPC4; i += 1024) {
        const int4 s4 = src4[i];
        const int4 d4 = dst4[i];
        const unsigned q0 = qs[d4.x];
        const unsigned q1 = qs[d4.y];
        const unsigned q2 = qs[d4.z];
        const unsigned q3 = qs[d4.w];
        atomicAdd(&cs[((unsigned)s4.x) >> 1], q0 << ((s4.x & 1) << 4));
        atomicAdd(&cs[((unsigned)s4.y) >> 1], q1 << ((s4.y & 1) << 4));
        atomicAdd(&cs[((unsigned)s4.z) >> 1], q2 << ((s4.z & 1) << 4));
        atomicAdd(&cs[((unsigned)s4.w) >> 1], q3 << ((s4.w & 1) << 4));
    }
    __syncthreads();
    unsigned* __restrict__ out = cpart + (size_t)(b * CHUNKS + chunk) * NWORDC;
    for (int i = threadIdx.x; i < NWORDC; i += 1024) out[i] = cs[i];
}

// ---------------------------------------------------------------------------
// K4 (was K5): fused w + pool. Block (c,b) owns nodes [c*6250,(c+1)*6250):
//  - reduce its 3125 cpart words (8 strided chunks) + dinv -> wlds in LDS
//    (folds old w_kernel: removes 6.4 MB w write + 6.4 MB read + K4 launch)
//  - pooled weighted column-sum, float4, 640 threads (10 waves/CU), fixed
//    channel phase; node index strength-reduced (ln += 256 per iteration,
//    since 640*4 % 10 == 0). Per-wave LDS accumulators, no global atomics.
// Keeps K6 (MLP) separate - R3 showed the last-block MLP fold regresses.
// ---------------------------------------------------------------------------
__global__ __launch_bounds__(PTHREADS) void pool_kernel(const unsigned* __restrict__ cpart,
                                                        const float* __restrict__ dinv,
                                                        const float* __restrict__ xg,
                                                        float* __restrict__ spart) {
    const int chunk = blockIdx.x, b = blockIdx.y;  // grid (8, 32)
    __shared__ float wlds[6250];                   // 25 KB w-slice
    __shared__ float sacc[PTHREADS / 64][10];
    const int tid = threadIdx.x;

    // ---- w-slice: w[n] = dinv*(c+dinv) for this block's 6250 nodes ----
    const int wbase = chunk * (NWORDC / 8);        // 3125 u16-pair words
    for (int li = tid; li < NWORDC / 8; li += PTHREADS) {
        const unsigned* __restrict__ p =
            cpart + (size_t)(b * CHUNKS) * NWORDC + wbase + li;
        unsigned c0 = 0, c1 = 0;
#pragma unroll
        for (int ch = 0; ch < CHUNKS; ++ch) {
            const unsigned v = p[(size_t)ch * NWORDC];
            c0 += v & 0xFFFF; c1 += v >> 16;
        }
        const int node = 2 * (wbase + li);
        const float2 d = *((const float2*)(dinv + (size_t)b * N_NODES + node));
        wlds[2 * li]     = d.x * ((float)c0 * (1.0f / QSCALE) + d.x);
        wlds[2 * li + 1] = d.y * ((float)c1 * (1.0f / QSCALE) + d.y);
    }
    const int wave = tid >> 6;
    if ((tid & 63) < 10) sacc[wave][tid & 63] = 0.0f;
    __syncthreads();

    // ---- pooled weighted column-sum from LDS w ----
    const float4* __restrict__ xg4 = (const float4*)xg;
    const int base4 = b * 125000 + chunk * 15625;  // float4 index; 4*base4 % 10 == 0
    const int r = (4 * tid) % 10;                  // element phase, fixed per lane
    int ln = (4 * tid) / 10;                       // local node; +256 per iteration
    float a0 = 0.0f, a1 = 0.0f, a2 = 0.0f, a3 = 0.0f;
    for (int j = tid; j < 15625; j += PTHREADS, ln += 256) {
        const float4 v = xg4[base4 + j];
        const float w0 = wlds[ln];
        const float w1 = (r == 8) ? wlds[ln + 1] : w0;  // r==8: z,w cross node boundary
        a0 += v.x * w0;
        a1 += v.y * w0;
        a2 += v.z * w1;
        a3 += v.w * w1;
    }
    atomicAdd(&sacc[wave][r], a0);
    atomicAdd(&sacc[wave][(r + 1) % 10], a1);
    atomicAdd(&sacc[wave][(r + 2) % 10], a2);
    atomicAdd(&sacc[wave][(r + 3) % 10], a3);
    __syncthreads();
    if (tid < 10) {
        float v = 0.0f;
#pragma unroll
        for (int wv = 0; wv < PTHREADS / 64; ++wv) v += sacc[wv][tid];
        spart[(b * CHUNKS + chunk) * 16 + tid] = v;
    }
}

// ---------------------------------------------------------------------------
// K5: reduce pool partials + tiny MLP + log_softmax(axis=0). One block.
// ---------------------------------------------------------------------------
__global__ __launch_bounds__(512) void mlp_kernel(const float* __restrict__ spart,
                           const float* __restrict__ x,
                           const float* __restrict__ W_gcn,
                           const float* __restrict__ b_gcn,
                           const float* __restrict__ W1, const float* __restrict__ b1,
                           const float* __restrict__ W2, const float* __restrict__ b2,
                           const float* __restrict__ Wo, const float* __restrict__ bo,
                           float* __restrict__ out) {
    __shared__ float ssum[32][10];
    __shared__ float h0[32][20];
    __shared__ float h1[32][80];
    __shared__ float h2[32][160];
    __shared__ float o[32][4];
    const int tid = threadIdx.x;

    for (int idx = tid; idx < 32 * 10; idx += blockDim.x) {
        const int b = idx / 10, k = idx % 10;
        float v = 0.0f;
#pragma unroll
        for (int c = 0; c < CHUNKS; ++c) v += spart[(b * CHUNKS + c) * 16 + k];
        ssum[b][k] = v;
    }
    __syncthreads();

    for (int idx = tid; idx < 32 * 20; idx += blockDim.x) {
        const int b = idx / 20, j = idx % 20;
        float v;
        if (j < 10) {
            v = 0.0f;
#pragma unroll
            for (int k = 0; k < 10; ++k) v += ssum[b][k] * W_gcn[k * 10 + j];
            v = v * (1.0f / (float)N_NODES) + b_gcn[j];
        } else {
            v = x[b * 10 + (j - 10)];
        }
        h0[b][j] = v;
    }
    __syncthreads();

    for (int idx = tid; idx < 32 * 80; idx += blockDim.x) {
        const int b = idx / 80, j = idx % 80;
        float v = b1[j];
#pragma unroll
        for (int k = 0; k < 20; ++k) v += h0[b][k] * W1[k * 80 + j];
        h1[b][j] = (v > 0.0f) ? v : 0.01f * v;
    }
    __syncthreads();

    for (int idx = tid; idx < 32 * 160; idx += blockDim.x) {
        const int b = idx / 160, j = idx % 160;
        float v = b2[j];
        for (int k = 0; k < 80; ++k) v += h1[b][k] * W2[k * 160 + j];
        h2[b][j] = (v > 0.0f) ? v : 0.01f * v;
    }
    __syncthreads();

    for (int idx = tid; idx < 32 * 4; idx += blockDim.x) {
        const int b = idx / 4, j = idx % 4;
        float v = bo[j];
        for (int k = 0; k < 160; ++k) v += h2[b][k] * Wo[k * 4 + j];
        o[b][j] = v;
    }
    __syncthreads();

    if (tid < 4) {
        float m = -1e30f;
        for (int b = 0; b < 32; ++b) m = fmaxf(m, o[b][tid]);
        float lse = 0.0f;
        for (int b = 0; b < 32; ++b) lse += expf(o[b][tid] - m);
        lse = logf(lse);
        for (int b = 0; b < 32; ++b) out[b * 4 + tid] = o[b][tid] - m - lse;
    }
}

extern "C" void kernel_launch(void* const* d_in, const int* in_sizes, int n_in,
                              void* d_out, int out_size, void* d_ws, size_t ws_size,
                              hipStream_t stream) {
    (void)in_sizes; (void)n_in; (void)out_size; (void)ws_size;
    const float* x      = (const float*)d_in[0];
    const float* gcn_x  = (const float*)d_in[1];
    const int*   ei     = (const int*)d_in[2];
    const float* W_gcn  = (const float*)d_in[3];
    const float* b_gcn  = (const float*)d_in[4];
    const float* W1     = (const float*)d_in[5];
    const float* b1     = (const float*)d_in[6];
    const float* W2     = (const float*)d_in[7];
    const float* b2     = (const float*)d_in[8];
    const float* Wo     = (const float*)d_in[9];
    const float* bo     = (const float*)d_in[10];
    float* out = (float*)d_out;

    // workspace layout (offsets in bytes):
    //   partials region [25.6 MB] @ 0     (hist uses 12.8 MB of it; cscat 25.6 MB)
    //   dinv     [32*50000 f32]   @ 25,600,000 (6.4 MB)
    //   qd8      [32*12500 u32]   @ 32,000,000 (1.6 MB)
    //   spart    [32*8*16 f32]    @ 33,600,000 (16 KB)    total ~33.6 MB
    unsigned* partials = (unsigned*)d_ws;
    float*    dinv     = (float*)((char*)d_ws + (size_t)BATCH * CHUNKS * NWORDC * 4);
    unsigned* qd8      = (unsigned*)((char*)dinv + (size_t)BATCH * N_NODES * 4);
    float*    spart    = (float*)((char*)qd8 + (size_t)BATCH * NWORD8 * 4);

    // 150 KB dynamic LDS for c-histogram (100 KB) + u8 dinv table (50 KB)
    hipFuncSetAttribute((const void*)cscat_kernel,
                        hipFuncAttributeMaxDynamicSharedMemorySize,
                        (NWORDC + NWORD8) * 4);

    {   // K1: degree histograms (8 chunks, 256 blocks -> 1/CU)
        dim3 grid(CHUNKS, BATCH);
        hist_kernel<<<grid, 1024, 0, stream>>>(ei, partials);
    }
    {   // K2: reduce -> dinv (f32), qd8 (u8 packed)
        const int n = BATCH * NWORD8;
        dinv_kernel<<<(n + 255) / 256, 256, 0, stream>>>(partials, dinv, qd8);
    }
    {   // K3: full-range c-scatter, LDS-resident gather table (150 KB LDS)
        cscat_kernel<<<256, 1024, (NWORDC + NWORD8) * 4, stream>>>(ei, qd8, partials);
    }
    {   // K4: fused w + pool (float4, 10 waves/CU, w in LDS, no global atomics)
        dim3 grid(CHUNKS, BATCH);
        pool_kernel<<<grid, PTHREADS, 0, stream>>>(partials, dinv, gcn_x, spart);
    }
    mlp_kernel<<<1, 512, 0, stream>>>(spart, x, W_gcn, b_gcn, W1, b1, W2, b2, Wo, bo, out);
}

// Round 6
// 396.354 us; speedup vs baseline: 2.2685x; 1.0035x over previous
//
#include <hip/hip_runtime.h>

#define N_NODES 50000
#define N_EDGES 800000
#define BATCH   32
#define NWORD8  12500   // N_NODES/4 u32 words (u8-packed deg counts / qd8 table)
#define NWORDC  25000   // N_NODES/2 u32 words, u16-packed c (full range, 100 KB)
#define CHUNKS  8       // edge chunks for hist AND cscat (100K edges each)
#define EPC4    25000   // int4 edge loads per chunk (= 100000 edges)
#define QSCALE  255.0f
#define PTHREADS 640    // pool threads: 640*4 % 10 == 0 keeps per-lane phase const

// XCD-locality scheme (heuristic XCD = dispatch_index % 8, grid-stride safe):
// every kernel maps batch b so that its blocks satisfy id % 8 == b & 7.
// Then partials[b] (K1->K2), qd8[b]/dinv[b] (K2->K3/K4) and cpart[b] (K3->K4)
// are produced and consumed in the SAME XCD's 4 MB L2 (4 batches x ~850 KB
// per XCD fits). If the mapping heuristic is wrong this is perf-neutral.

// ---------------------------------------------------------------------------
// K1: per-(batch,chunk) degree histogram in LDS (u8 packed x4 per u32 word).
// grid (32, 8): b = blockIdx.x -> id%8 == b&7 (partials stay in local L2).
// Per-chunk degree is Binomial(100K, 1/50K): mean 2, P(>255) ~ 0 -> u8 safe.
// ---------------------------------------------------------------------------
__global__ __launch_bounds__(1024) void hist_kernel(const int* __restrict__ ei,
                                                    unsigned* __restrict__ partials) {
    const int b = blockIdx.x, chunk = blockIdx.y;   // grid (32, 8)
    __shared__ unsigned cnt[NWORD8];  // 50 KB
    for (int i = threadIdx.x; i < NWORD8; i += 1024) cnt[i] = 0;
    __syncthreads();
    const int4* __restrict__ dst4 =
        (const int4*)(ei + (size_t)b * (2 * N_EDGES) + N_EDGES) + (size_t)chunk * EPC4;
    for (int i = threadIdx.x; i < EPC4; i += 1024) {
        const int4 v = dst4[i];
        atomicAdd(&cnt[((unsigned)v.x) >> 2], 1u << ((v.x & 3) * 8));
        atomicAdd(&cnt[((unsigned)v.y) >> 2], 1u << ((v.y & 3) * 8));
        atomicAdd(&cnt[((unsigned)v.z) >> 2], 1u << ((v.z & 3) * 8));
        atomicAdd(&cnt[((unsigned)v.w) >> 2], 1u << ((v.w & 3) * 8));
    }
    __syncthreads();
    unsigned* __restrict__ out = partials + (size_t)(b * CHUNKS + chunk) * NWORD8;
    for (int i = threadIdx.x; i < NWORD8; i += 1024) out[i] = cnt[i];
}

// ---------------------------------------------------------------------------
// K2: reduce degree partials -> dinv[b][n] = rsqrt(count+1) (f32)
//     and qd8 = round(dinv * 255) packed x4 per u32 (LDS gather table for K3).
// grid (32, 49): b = blockIdx.x -> id%8 == b&7: reads partials[b] from the
// local L2, writes dinv[b]/qd8[b] into it for K3/K4.
// ---------------------------------------------------------------------------
__global__ void dinv_kernel(const unsigned* __restrict__ partials,
                            float* __restrict__ dinv,
                            unsigned* __restrict__ qd8) {
    const int b = blockIdx.x;
    const int i = blockIdx.y * 256 + threadIdx.x;   // word index within batch
    if (i >= NWORD8) return;
    const unsigned* __restrict__ p = partials + (size_t)(b * CHUNKS) * NWORD8 + i;
    unsigned d0 = 0, d1 = 0, d2 = 0, d3 = 0;
#pragma unroll
    for (int c = 0; c < CHUNKS; ++c) {
        const unsigned v = p[(size_t)c * NWORD8];
        d0 += v & 0xFF; d1 += (v >> 8) & 0xFF; d2 += (v >> 16) & 0xFF; d3 += v >> 24;
    }
    const float i0 = rsqrtf((float)(d0 + 1));
    const float i1 = rsqrtf((float)(d1 + 1));
    const float i2 = rsqrtf((float)(d2 + 1));
    const float i3 = rsqrtf((float)(d3 + 1));
    float4* dv4 = (float4*)(dinv + (size_t)b * N_NODES) + i;
    *dv4 = make_float4(i0, i1, i2, i3);
    const unsigned q0 = __float2uint_rn(i0 * QSCALE);
    const unsigned q1 = __float2uint_rn(i1 * QSCALE);
    const unsigned q2 = __float2uint_rn(i2 * QSCALE);
    const unsigned q3 = __float2uint_rn(i3 * QSCALE);
    qd8[(size_t)b * NWORD8 + i] = q0 | (q1 << 8) | (q2 << 16) | (q3 << 24);
}

// ---------------------------------------------------------------------------
// K3: c[n] = sum over out-edges of n of dinv[dst], u16 fixed-point histogram
// over the FULL node range. dst-side dinv table lives in LDS as u8 (50 KB):
// the random gather is a ds_read_u8, not a divergent global load.
// Dynamic LDS = 100 KB histogram + 50 KB qd8 = 150 KB; 256 blocks = 1/CU.
// id%8 == b&7 already (b = (id&7) + 8*bgroup): cpart[b] lands in local L2.
// ---------------------------------------------------------------------------
__global__ __launch_bounds__(1024) void cscat_kernel(const int* __restrict__ ei,
                                                     const unsigned* __restrict__ qd8,
                                                     unsigned* __restrict__ cpart) {
    extern __shared__ unsigned smem[];           // [0,25000): cs, [25000,37500): qd8
    unsigned* cs = smem;
    const unsigned char* qs = (const unsigned char*)(smem + NWORDC);
    const int id = blockIdx.x;  // 256 = 8 xcd * 4 bgroup * 8 chunk
    const int b = (id & 7) + 8 * ((id >> 3) & 3);
    const int chunk = id >> 5;
    for (int i = threadIdx.x; i < NWORDC; i += 1024) cs[i] = 0;
    {   // stage the batch's u8 dinv table into LDS (coalesced, 50 KB)
        const unsigned* __restrict__ src = qd8 + (size_t)b * NWORD8;
        unsigned* dst = smem + NWORDC;
        for (int i = threadIdx.x; i < NWORD8; i += 1024) dst[i] = src[i];
    }
    __syncthreads();
    const int* eb = ei + (size_t)b * (2 * N_EDGES);
    const int4* __restrict__ src4 = (const int4*)eb + (size_t)chunk * EPC4;
    const int4* __restrict__ dst4 = (const int4*)(eb + N_EDGES) + (size_t)chunk * EPC4;
    for (int i = threadIdx.x; i < EPC4; i += 1024) {
        const int4 s4 = src4[i];
        const int4 d4 = dst4[i];
        const unsigned q0 = qs[d4.x];
        const unsigned q1 = qs[d4.y];
        const unsigned q2 = qs[d4.z];
        const unsigned q3 = qs[d4.w];
        atomicAdd(&cs[((unsigned)s4.x) >> 1], q0 << ((s4.x & 1) << 4));
        atomicAdd(&cs[((unsigned)s4.y) >> 1], q1 << ((s4.y & 1) << 4));
        atomicAdd(&cs[((unsigned)s4.z) >> 1], q2 << ((s4.z & 1) << 4));
        atomicAdd(&cs[((unsigned)s4.w) >> 1], q3 << ((s4.w & 1) << 4));
    }
    __syncthreads();
    unsigned* __restrict__ out = cpart + (size_t)(b * CHUNKS + chunk) * NWORDC;
    for (int i = threadIdx.x; i < NWORDC; i += 1024) out[i] = cs[i];
}

// ---------------------------------------------------------------------------
// K4: fused w + pool. grid (32, 8): b = blockIdx.x -> id%8 == b&7: reads
// cpart[b] + dinv[b] from the XCD-local L2 where K3/K2 left them.
// Block (b,c) owns nodes [c*6250,(c+1)*6250): reduce its 3125 cpart words
// (8 strided chunks) + dinv -> wlds in LDS, then pooled weighted column-sum
// (float4, 640 threads, fixed channel phase, ln += 256 strength reduction).
// ---------------------------------------------------------------------------
__global__ __launch_bounds__(PTHREADS) void pool_kernel(const unsigned* __restrict__ cpart,
                                                        const float* __restrict__ dinv,
                                                        const float* __restrict__ xg,
                                                        float* __restrict__ spart) {
    const int b = blockIdx.x, chunk = blockIdx.y;  // grid (32, 8)
    __shared__ float wlds[6250];                   // 25 KB w-slice
    __shared__ float sacc[PTHREADS / 64][10];
    const int tid = threadIdx.x;

    // ---- w-slice: w[n] = dinv*(c+dinv) for this block's 6250 nodes ----
    const int wbase = chunk * (NWORDC / 8);        // 3125 u16-pair words
    for (int li = tid; li < NWORDC / 8; li += PTHREADS) {
        const unsigned* __restrict__ p =
            cpart + (size_t)(b * CHUNKS) * NWORDC + wbase + li;
        unsigned c0 = 0, c1 = 0;
#pragma unroll
        for (int ch = 0; ch < CHUNKS; ++ch) {
            const unsigned v = p[(size_t)ch * NWORDC];
            c0 += v & 0xFFFF; c1 += v >> 16;
        }
        const int node = 2 * (wbase + li);
        const float2 d = *((const float2*)(dinv + (size_t)b * N_NODES + node));
        wlds[2 * li]     = d.x * ((float)c0 * (1.0f / QSCALE) + d.x);
        wlds[2 * li + 1] = d.y * ((float)c1 * (1.0f / QSCALE) + d.y);
    }
    const int wave = tid >> 6;
    if ((tid & 63) < 10) sacc[wave][tid & 63] = 0.0f;
    __syncthreads();

    // ---- pooled weighted column-sum from LDS w ----
    const float4* __restrict__ xg4 = (const float4*)xg;
    const int base4 = b * 125000 + chunk * 15625;  // float4 index; 4*base4 % 10 == 0
    const int r = (4 * tid) % 10;                  // element phase, fixed per lane
    int ln = (4 * tid) / 10;                       // local node; +256 per iteration
    float a0 = 0.0f, a1 = 0.0f, a2 = 0.0f, a3 = 0.0f;
    for (int j = tid; j < 15625; j += PTHREADS, ln += 256) {
        const float4 v = xg4[base4 + j];
        const float w0 = wlds[ln];
        const float w1 = (r == 8) ? wlds[ln + 1] : w0;  // r==8: z,w cross node boundary
        a0 += v.x * w0;
        a1 += v.y * w0;
        a2 += v.z * w1;
        a3 += v.w * w1;
    }
    atomicAdd(&sacc[wave][r], a0);
    atomicAdd(&sacc[wave][(r + 1) % 10], a1);
    atomicAdd(&sacc[wave][(r + 2) % 10], a2);
    atomicAdd(&sacc[wave][(r + 3) % 10], a3);
    __syncthreads();
    if (tid < 10) {
        float v = 0.0f;
#pragma unroll
        for (int wv = 0; wv < PTHREADS / 64; ++wv) v += sacc[wv][tid];
        spart[(b * CHUNKS + chunk) * 16 + tid] = v;
    }
}

// ---------------------------------------------------------------------------
// K5: reduce pool partials + tiny MLP + log_softmax(axis=0). One block.
// ---------------------------------------------------------------------------
__global__ __launch_bounds__(512) void mlp_kernel(const float* __restrict__ spart,
                           const float* __restrict__ x,
                           const float* __restrict__ W_gcn,
                           const float* __restrict__ b_gcn,
                           const float* __restrict__ W1, const float* __restrict__ b1,
                           const float* __restrict__ W2, const float* __restrict__ b2,
                           const float* __restrict__ Wo, const float* __restrict__ bo,
                           float* __restrict__ out) {
    __shared__ float ssum[32][10];
    __shared__ float h0[32][20];
    __shared__ float h1[32][80];
    __shared__ float h2[32][160];
    __shared__ float o[32][4];
    const int tid = threadIdx.x;

    for (int idx = tid; idx < 32 * 10; idx += blockDim.x) {
        const int b = idx / 10, k = idx % 10;
        float v = 0.0f;
#pragma unroll
        for (int c = 0; c < CHUNKS; ++c) v += spart[(b * CHUNKS + c) * 16 + k];
        ssum[b][k] = v;
    }
    __syncthreads();

    for (int idx = tid; idx < 32 * 20; idx += blockDim.x) {
        const int b = idx / 20, j = idx % 20;
        float v;
        if (j < 10) {
            v = 0.0f;
#pragma unroll
            for (int k = 0; k < 10; ++k) v += ssum[b][k] * W_gcn[k * 10 + j];
            v = v * (1.0f / (float)N_NODES) + b_gcn[j];
        } else {
            v = x[b * 10 + (j - 10)];
        }
        h0[b][j] = v;
    }
    __syncthreads();

    for (int idx = tid; idx < 32 * 80; idx += blockDim.x) {
        const int b = idx / 80, j = idx % 80;
        float v = b1[j];
#pragma unroll
        for (int k = 0; k < 20; ++k) v += h0[b][k] * W1[k * 80 + j];
        h1[b][j] = (v > 0.0f) ? v : 0.01f * v;
    }
    __syncthreads();

    for (int idx = tid; idx < 32 * 160; idx += blockDim.x) {
        const int b = idx / 160, j = idx % 160;
        float v = b2[j];
        for (int k = 0; k < 80; ++k) v += h1[b][k] * W2[k * 160 + j];
        h2[b][j] = (v > 0.0f) ? v : 0.01f * v;
    }
    __syncthreads();

    for (int idx = tid; idx < 32 * 4; idx += blockDim.x) {
        const int b = idx / 4, j = idx % 4;
        float v = bo[j];
        for (int k = 0; k < 160; ++k) v += h2[b][k] * Wo[k * 4 + j];
        o[b][j] = v;
    }
    __syncthreads();

    if (tid < 4) {
        float m = -1e30f;
        for (int b = 0; b < 32; ++b) m = fmaxf(m, o[b][tid]);
        float lse = 0.0f;
        for (int b = 0; b < 32; ++b) lse += expf(o[b][tid] - m);
        lse = logf(lse);
        for (int b = 0; b < 32; ++b) out[b * 4 + tid] = o[b][tid] - m - lse;
    }
}

extern "C" void kernel_launch(void* const* d_in, const int* in_sizes, int n_in,
                              void* d_out, int out_size, void* d_ws, size_t ws_size,
                              hipStream_t stream) {
    (void)in_sizes; (void)n_in; (void)out_size; (void)ws_size;
    const float* x      = (const float*)d_in[0];
    const float* gcn_x  = (const float*)d_in[1];
    const int*   ei     = (const int*)d_in[2];
    const float* W_gcn  = (const float*)d_in[3];
    const float* b_gcn  = (const float*)d_in[4];
    const float* W1     = (const float*)d_in[5];
    const float* b1     = (const float*)d_in[6];
    const float* W2     = (const float*)d_in[7];
    const float* b2     = (const float*)d_in[8];
    const float* Wo     = (const float*)d_in[9];
    const float* bo     = (const float*)d_in[10];
    float* out = (float*)d_out;

    // workspace layout (offsets in bytes):
    //   partials region [25.6 MB] @ 0     (hist uses 12.8 MB of it; cscat 25.6 MB)
    //   dinv     [32*50000 f32]   @ 25,600,000 (6.4 MB)
    //   qd8      [32*12500 u32]   @ 32,000,000 (1.6 MB)
    //   spart    [32*8*16 f32]    @ 33,600,000 (16 KB)    total ~33.6 MB
    unsigned* partials = (unsigned*)d_ws;
    float*    dinv     = (float*)((char*)d_ws + (size_t)BATCH * CHUNKS * NWORDC * 4);
    unsigned* qd8      = (unsigned*)((char*)dinv + (size_t)BATCH * N_NODES * 4);
    float*    spart    = (float*)((char*)qd8 + (size_t)BATCH * NWORD8 * 4);

    // 150 KB dynamic LDS for c-histogram (100 KB) + u8 dinv table (50 KB)
    hipFuncSetAttribute((const void*)cscat_kernel,
                        hipFuncAttributeMaxDynamicSharedMemorySize,
                        (NWORDC + NWORD8) * 4);

    {   // K1: degree histograms, batch-major grid for XCD locality
        dim3 grid(BATCH, CHUNKS);
        hist_kernel<<<grid, 1024, 0, stream>>>(ei, partials);
    }
    {   // K2: reduce -> dinv (f32), qd8 (u8 packed), batch-major grid
        dim3 grid(BATCH, (NWORD8 + 255) / 256);
        dinv_kernel<<<grid, 256, 0, stream>>>(partials, dinv, qd8);
    }
    {   // K3: full-range c-scatter, LDS-resident gather table (150 KB LDS)
        cscat_kernel<<<256, 1024, (NWORDC + NWORD8) * 4, stream>>>(ei, qd8, partials);
    }
    {   // K4: fused w + pool, batch-major grid for XCD locality
        dim3 grid(BATCH, CHUNKS);
        pool_kernel<<<grid, PTHREADS, 0, stream>>>(partials, dinv, gcn_x, spart);
    }
    mlp_kernel<<<1, 512, 0, stream>>>(spart, x, W_gcn, b_gcn, W1, b1, W2, b2, Wo, bo, out);
}